// Round 1
// baseline (249.501 us; speedup 1.0000x reference)
//
#include <hip/hip_runtime.h>
#include <hip/hip_fp16.h>
#include <math.h>

#define NTOK 2048
#define HID  1024
#define FFN  2048
#define NEXP 8

#define BM 128
#define BN 128
#define BK 32
#define LDA 40            // BK + 8 pad (halfwords) -> 80B row stride, 2-way max conflict on b128
#define MAX_TILES 40      // sum ceil(cnt_e/BM) <= 4096/128 + 8 = 40

// workspace layout (bytes)
#define WS_COUNTS 0                         // 8 ints (zeroed each launch)
#define WS_SEG    32                        // 9 ints
#define WS_PROBS  128                       // NTOK*NEXP floats = 64KB
#define WS_LISTS  (128 + NTOK*NEXP*4)       // 8*NTOK ints = 64KB
#define WS_HBUF   262144                    // fp16 h buffer
#define HROWS     (MAX_TILES*BM)            // 5120 padded rows

typedef _Float16 half8 __attribute__((ext_vector_type(8)));
typedef float    f32x4 __attribute__((ext_vector_type(4)));

static __device__ __forceinline__ unsigned short f2h_bits(float f) {
  union { _Float16 h; unsigned short u; } v;
  v.h = (_Float16)f;
  return v.u;
}
static __device__ __forceinline__ unsigned pack2(float a, float b) {
  return (unsigned)f2h_bits(a) | ((unsigned)f2h_bits(b) << 16);
}

// ---------------- router: logits -> softmax -> top2 -> scatter ----------------
__global__ __launch_bounds__(64) void moe_router(
    const float* __restrict__ x, const float* __restrict__ rw,
    int* __restrict__ counts, int* __restrict__ lists, float* __restrict__ probs)
{
  const int t = blockIdx.x;
  const int lane = threadIdx.x;
  const float* xr = x + (size_t)t * HID;

  float acc[NEXP];
#pragma unroll
  for (int e = 0; e < NEXP; ++e) acc[e] = 0.f;

  for (int h = lane; h < HID; h += 64) {
    float xv = xr[h];
    const float4* rp = reinterpret_cast<const float4*>(rw + (size_t)h * NEXP);
    float4 a = rp[0], b = rp[1];
    acc[0] += xv * a.x; acc[1] += xv * a.y; acc[2] += xv * a.z; acc[3] += xv * a.w;
    acc[4] += xv * b.x; acc[5] += xv * b.y; acc[6] += xv * b.z; acc[7] += xv * b.w;
  }
#pragma unroll
  for (int off = 32; off > 0; off >>= 1) {
#pragma unroll
    for (int e = 0; e < NEXP; ++e) acc[e] += __shfl_down(acc[e], off);
  }

  if (lane == 0) {
    float m = acc[0];
#pragma unroll
    for (int e = 1; e < NEXP; ++e) m = fmaxf(m, acc[e]);
    float p[NEXP];
#pragma unroll
    for (int e = 0; e < NEXP; ++e) p[e] = expf(acc[e] - m);
    // top-2: strict > keeps lowest index on ties (matches lax.top_k)
    int i0 = 0;
#pragma unroll
    for (int e = 1; e < NEXP; ++e) if (p[e] > p[i0]) i0 = e;
    int i1 = -1;
#pragma unroll
    for (int e = 0; e < NEXP; ++e) {
      if (e == i0) continue;
      if (i1 < 0 || p[e] > p[i1]) i1 = e;
    }
    const float inv = 1.f / (p[i0] + p[i1]);
    probs[t * NEXP + i0] = p[i0] * inv;
    probs[t * NEXP + i1] = p[i1] * inv;
    int pos0 = atomicAdd(&counts[i0], 1); lists[i0 * NTOK + pos0] = t;
    int pos1 = atomicAdd(&counts[i1], 1); lists[i1 * NTOK + pos1] = t;
  }
}

// ---------------- padded segment offsets ----------------
__global__ void moe_segoff(const int* __restrict__ counts, int* __restrict__ seg) {
  if (threadIdx.x == 0 && blockIdx.x == 0) {
    int run = 0;
    for (int e = 0; e < NEXP; ++e) {
      seg[e] = run;
      run += ((counts[e] + BM - 1) / BM) * BM;
    }
    seg[NEXP] = run;
  }
}

// ---------------- GEMM1: h = gelu(x[tok] @ w1[e]) -> fp16 hbuf ----------------
__global__ __launch_bounds__(256) void moe_gemm1(
    const float* __restrict__ x, const float* __restrict__ w1,
    const int* __restrict__ counts, const int* __restrict__ seg,
    const int* __restrict__ lists, unsigned short* __restrict__ hbuf)
{
  const int tile = blockIdx.x >> 4;     // FFN/BN = 16 col tiles
  const int jcol = blockIdx.x & 15;
  const int rb = tile * BM;
  if (rb >= seg[NEXP]) return;
  int e = 0;
#pragma unroll
  for (int q = 1; q < NEXP; ++q) if (seg[q] <= rb) e = q;
  const int cnt = counts[e];
  const int rloc0 = rb - seg[e];

  __shared__ int tokL[BM];
  __shared__ unsigned short Asm[BM][LDA];
  __shared__ unsigned short Bsm[BN][LDA];

  const int tid = threadIdx.x;
  if (tid < BM) {
    int rl = rloc0 + tid;
    tokL[tid] = (rl < cnt) ? lists[e * NTOK + rl] : 0;
  }
  __syncthreads();

  const int lane = tid & 63;
  const int wid = tid >> 6;
  const int wr = (wid >> 1) * 64;
  const int wc = (wid & 1) * 64;
  const int lr = (lane >> 4) * 4;
  const int lc = lane & 15;
  const int kfrag = (lane >> 4) * 8;

  f32x4 acc[4][4];
#pragma unroll
  for (int m = 0; m < 4; ++m)
#pragma unroll
    for (int n = 0; n < 4; ++n)
      acc[m][n] = (f32x4){0.f, 0.f, 0.f, 0.f};

  const int srow = tid >> 1;            // A row index / B col index
  const int skoff = (tid & 1) * 16;     // k sub-offset
  const float* bbase = w1 + (size_t)e * HID * FFN + (size_t)jcol * BN + srow;

  for (int kk = 0; kk < HID; kk += BK) {
    const int tok = tokL[srow];
    const float4* ap = reinterpret_cast<const float4*>(x + (size_t)tok * HID + kk + skoff);
    float4 a0 = ap[0], a1 = ap[1], a2 = ap[2], a3 = ap[3];
    float bv[16];
    const float* bp = bbase + (size_t)(kk + skoff) * FFN;
#pragma unroll
    for (int i = 0; i < 16; ++i) bv[i] = bp[(size_t)i * FFN];

    __syncthreads();
    uint4* adst = reinterpret_cast<uint4*>(&Asm[srow][skoff]);
    adst[0] = (uint4){pack2(a0.x,a0.y), pack2(a0.z,a0.w), pack2(a1.x,a1.y), pack2(a1.z,a1.w)};
    adst[1] = (uint4){pack2(a2.x,a2.y), pack2(a2.z,a2.w), pack2(a3.x,a3.y), pack2(a3.z,a3.w)};
    uint4* bdst = reinterpret_cast<uint4*>(&Bsm[srow][skoff]);
    bdst[0] = (uint4){pack2(bv[0],bv[1]), pack2(bv[2],bv[3]), pack2(bv[4],bv[5]), pack2(bv[6],bv[7])};
    bdst[1] = (uint4){pack2(bv[8],bv[9]), pack2(bv[10],bv[11]), pack2(bv[12],bv[13]), pack2(bv[14],bv[15])};
    __syncthreads();

    half8 af[4], bf[4];
#pragma unroll
    for (int m = 0; m < 4; ++m)
      af[m] = *reinterpret_cast<const half8*>(&Asm[wr + m*16 + lc][kfrag]);
#pragma unroll
    for (int n = 0; n < 4; ++n)
      bf[n] = *reinterpret_cast<const half8*>(&Bsm[wc + n*16 + lc][kfrag]);
#pragma unroll
    for (int m = 0; m < 4; ++m)
#pragma unroll
      for (int n = 0; n < 4; ++n)
        acc[m][n] = __builtin_amdgcn_mfma_f32_16x16x32_f16(af[m], bf[n], acc[m][n], 0, 0, 0);
  }

#pragma unroll
  for (int m = 0; m < 4; ++m) {
#pragma unroll
    for (int r = 0; r < 4; ++r) {
      const int rl = rloc0 + wr + m*16 + lr + r;
      if (rl >= cnt) continue;
      unsigned short* hp = hbuf + (size_t)(rb + wr + m*16 + lr + r) * FFN + jcol*BN + wc + lc;
#pragma unroll
      for (int n = 0; n < 4; ++n) {
        float v = acc[m][n][r];
        float g = 0.5f * v * (1.f + erff(v * 0.70710678118f));   // exact erf-gelu
        hp[n*16] = f2h_bits(g);
      }
    }
  }
}

// ---------------- GEMM2: out[tok] += p * (h @ w2[e]) ----------------
__global__ __launch_bounds__(256) void moe_gemm2(
    const unsigned short* __restrict__ hbuf, const float* __restrict__ w2,
    const int* __restrict__ counts, const int* __restrict__ seg,
    const int* __restrict__ lists, const float* __restrict__ probs,
    float* __restrict__ out)
{
  const int tile = blockIdx.x >> 3;     // HID/BN = 8 col tiles
  const int jcol = blockIdx.x & 7;
  const int rb = tile * BM;
  if (rb >= seg[NEXP]) return;
  int e = 0;
#pragma unroll
  for (int q = 1; q < NEXP; ++q) if (seg[q] <= rb) e = q;
  const int cnt = counts[e];
  const int rloc0 = rb - seg[e];

  __shared__ int tokL[BM];
  __shared__ float pL[BM];
  __shared__ unsigned short Asm[BM][LDA];
  __shared__ unsigned short Bsm[BN][LDA];

  const int tid = threadIdx.x;
  if (tid < BM) {
    int rl = rloc0 + tid;
    if (rl < cnt) {
      int tk = lists[e * NTOK + rl];
      tokL[tid] = tk;
      pL[tid] = probs[tk * NEXP + e];
    } else { tokL[tid] = 0; pL[tid] = 0.f; }
  }
  __syncthreads();

  const int lane = tid & 63;
  const int wid = tid >> 6;
  const int wr = (wid >> 1) * 64;
  const int wc = (wid & 1) * 64;
  const int lr = (lane >> 4) * 4;
  const int lc = lane & 15;
  const int kfrag = (lane >> 4) * 8;

  f32x4 acc[4][4];
#pragma unroll
  for (int m = 0; m < 4; ++m)
#pragma unroll
    for (int n = 0; n < 4; ++n)
      acc[m][n] = (f32x4){0.f, 0.f, 0.f, 0.f};

  const int srow = tid >> 1;
  const int skoff = (tid & 1) * 16;
  const float* bbase = w2 + (size_t)e * FFN * HID + (size_t)jcol * BN + srow;
  const unsigned short* arow_p = hbuf + (size_t)(rb + srow) * FFN + skoff;

  for (int kk = 0; kk < FFN; kk += BK) {
    const uint4* ap = reinterpret_cast<const uint4*>(arow_p + kk);
    uint4 av0 = ap[0], av1 = ap[1];
    float bv[16];
    const float* bp = bbase + (size_t)(kk + skoff) * HID;
#pragma unroll
    for (int i = 0; i < 16; ++i) bv[i] = bp[(size_t)i * HID];

    __syncthreads();
    uint4* adst = reinterpret_cast<uint4*>(&Asm[srow][skoff]);
    adst[0] = av0; adst[1] = av1;
    uint4* bdst = reinterpret_cast<uint4*>(&Bsm[srow][skoff]);
    bdst[0] = (uint4){pack2(bv[0],bv[1]), pack2(bv[2],bv[3]), pack2(bv[4],bv[5]), pack2(bv[6],bv[7])};
    bdst[1] = (uint4){pack2(bv[8],bv[9]), pack2(bv[10],bv[11]), pack2(bv[12],bv[13]), pack2(bv[14],bv[15])};
    __syncthreads();

    half8 af[4], bf[4];
#pragma unroll
    for (int m = 0; m < 4; ++m)
      af[m] = *reinterpret_cast<const half8*>(&Asm[wr + m*16 + lc][kfrag]);
#pragma unroll
    for (int n = 0; n < 4; ++n)
      bf[n] = *reinterpret_cast<const half8*>(&Bsm[wc + n*16 + lc][kfrag]);
#pragma unroll
    for (int m = 0; m < 4; ++m)
#pragma unroll
      for (int n = 0; n < 4; ++n)
        acc[m][n] = __builtin_amdgcn_mfma_f32_16x16x32_f16(af[m], bf[n], acc[m][n], 0, 0, 0);
  }

#pragma unroll
  for (int m = 0; m < 4; ++m) {
#pragma unroll
    for (int r = 0; r < 4; ++r) {
      const int lrow = wr + m*16 + lr + r;
      const int rl = rloc0 + lrow;
      if (rl >= cnt) continue;
      const int tok = tokL[lrow];
      const float p = pL[lrow];
      float* op = out + (size_t)tok * HID + jcol*BN + wc + lc;
#pragma unroll
      for (int n = 0; n < 4; ++n)
        atomicAdd(&op[n*16], p * acc[m][n][r]);   // exactly 2 adds/element -> deterministic
    }
  }
}

extern "C" void kernel_launch(void* const* d_in, const int* in_sizes, int n_in,
                              void* d_out, int out_size, void* d_ws, size_t ws_size,
                              hipStream_t stream) {
  const float* x  = (const float*)d_in[0];
  const float* rw = (const float*)d_in[1];
  const float* w1 = (const float*)d_in[2];
  const float* w2 = (const float*)d_in[3];
  float* out = (float*)d_out;

  char* ws = (char*)d_ws;
  int*   counts = (int*)(ws + WS_COUNTS);
  int*   seg    = (int*)(ws + WS_SEG);
  float* probs  = (float*)(ws + WS_PROBS);
  int*   lists  = (int*)(ws + WS_LISTS);
  unsigned short* hbuf = (unsigned short*)(ws + WS_HBUF);

  hipMemsetAsync(ws, 0, 128, stream);                                   // counts
  hipMemsetAsync(d_out, 0, (size_t)NTOK * HID * sizeof(float), stream); // atomic target

  moe_router<<<NTOK, 64, 0, stream>>>(x, rw, counts, lists, probs);
  moe_segoff<<<1, 64, 0, stream>>>(counts, seg);
  moe_gemm1<<<MAX_TILES * (FFN / BN), 256, 0, stream>>>(x, w1, counts, seg, lists, hbuf);
  moe_gemm2<<<MAX_TILES * (HID / BN), 256, 0, stream>>>(hbuf, w2, counts, seg, lists, probs, out);
}

// Round 2
// 243.242 us; speedup vs baseline: 1.0257x; 1.0257x over previous
//
#include <hip/hip_runtime.h>
#include <hip/hip_fp16.h>
#include <math.h>

#define NTOK 2048
#define HID  1024
#define FFN  2048
#define NEXP 8

#define BM 128
#define BN 128
#define BK 32
#define LDA 40            // BK + 8 pad (halfwords) -> 80B row stride, 2-way max conflict on b128
#define MAX_TILES 40      // sum ceil(cnt_e/BM) <= 4096/128 + 8 = 40

// workspace layout (bytes)
#define WS_COUNTS 0                         // 8 ints (zeroed each launch)
#define WS_SEG    32                        // 9 ints
#define WS_PROBS  128                       // NTOK*NEXP floats = 64KB
#define WS_LISTS  (128 + NTOK*NEXP*4)       // 8*NTOK ints = 64KB
#define WS_HBUF   262144                    // fp16 h buffer

typedef _Float16 half8 __attribute__((ext_vector_type(8)));
typedef float    f32x4 __attribute__((ext_vector_type(4)));

static __device__ __forceinline__ unsigned short f2h_bits(float f) {
  union { _Float16 h; unsigned short u; } v;
  v.h = (_Float16)f;
  return v.u;
}
static __device__ __forceinline__ unsigned pack2(float a, float b) {
  return (unsigned)f2h_bits(a) | ((unsigned)f2h_bits(b) << 16);
}

// ---------------- router: logits -> softmax -> top2 -> scatter ----------------
__global__ __launch_bounds__(64) void moe_router(
    const float* __restrict__ x, const float* __restrict__ rw,
    int* __restrict__ counts, int* __restrict__ lists, float* __restrict__ probs)
{
  const int t = blockIdx.x;
  const int lane = threadIdx.x;
  const float* xr = x + (size_t)t * HID;

  float acc[NEXP];
#pragma unroll
  for (int e = 0; e < NEXP; ++e) acc[e] = 0.f;

  for (int h = lane; h < HID; h += 64) {
    float xv = xr[h];
    const float4* rp = reinterpret_cast<const float4*>(rw + (size_t)h * NEXP);
    float4 a = rp[0], b = rp[1];
    acc[0] += xv * a.x; acc[1] += xv * a.y; acc[2] += xv * a.z; acc[3] += xv * a.w;
    acc[4] += xv * b.x; acc[5] += xv * b.y; acc[6] += xv * b.z; acc[7] += xv * b.w;
  }
#pragma unroll
  for (int off = 32; off > 0; off >>= 1) {
#pragma unroll
    for (int e = 0; e < NEXP; ++e) acc[e] += __shfl_down(acc[e], off);
  }

  if (lane == 0) {
    float m = acc[0];
#pragma unroll
    for (int e = 1; e < NEXP; ++e) m = fmaxf(m, acc[e]);
    float p[NEXP];
#pragma unroll
    for (int e = 0; e < NEXP; ++e) p[e] = expf(acc[e] - m);
    // top-2: strict > keeps lowest index on ties (matches lax.top_k)
    int i0 = 0;
#pragma unroll
    for (int e = 1; e < NEXP; ++e) if (p[e] > p[i0]) i0 = e;
    int i1 = -1;
#pragma unroll
    for (int e = 0; e < NEXP; ++e) {
      if (e == i0) continue;
      if (i1 < 0 || p[e] > p[i1]) i1 = e;
    }
    const float inv = 1.f / (p[i0] + p[i1]);
    probs[t * NEXP + i0] = p[i0] * inv;
    probs[t * NEXP + i1] = p[i1] * inv;
    int pos0 = atomicAdd(&counts[i0], 1); lists[i0 * NTOK + pos0] = t;
    int pos1 = atomicAdd(&counts[i1], 1); lists[i1 * NTOK + pos1] = t;
  }
}

// ---------------- padded segment offsets ----------------
__global__ void moe_segoff(const int* __restrict__ counts, int* __restrict__ seg) {
  if (threadIdx.x == 0 && blockIdx.x == 0) {
    int run = 0;
    for (int e = 0; e < NEXP; ++e) {
      seg[e] = run;
      run += ((counts[e] + BM - 1) / BM) * BM;
    }
    seg[NEXP] = run;
  }
}

// ---------------- GEMM1: h = gelu(x[tok] @ w1[e]) -> fp16 hbuf ----------------
// Pipeline: {barrier; regs->LDS; barrier; prefetch next tile -> regs; ds_read+MFMA}
__global__ __launch_bounds__(256) void moe_gemm1(
    const float* __restrict__ x, const float* __restrict__ w1,
    const int* __restrict__ counts, const int* __restrict__ seg,
    const int* __restrict__ lists, unsigned short* __restrict__ hbuf)
{
  const int tile = blockIdx.x >> 4;     // FFN/BN = 16 col tiles
  const int jcol = blockIdx.x & 15;
  const int rb = tile * BM;
  if (rb >= seg[NEXP]) return;
  int e = 0;
#pragma unroll
  for (int q = 1; q < NEXP; ++q) if (seg[q] <= rb) e = q;
  const int cnt = counts[e];
  const int rloc0 = rb - seg[e];

  __shared__ int tokL[BM];
  __shared__ unsigned short Asm[BM][LDA];
  __shared__ unsigned short Bsm[BN][LDA];

  const int tid = threadIdx.x;
  if (tid < BM) {
    int rl = rloc0 + tid;
    tokL[tid] = (rl < cnt) ? lists[e * NTOK + rl] : 0;
  }
  __syncthreads();

  const int lane = tid & 63;
  const int wid = tid >> 6;
  const int wr = (wid >> 1) * 64;
  const int wc = (wid & 1) * 64;
  const int lr = (lane >> 4) * 4;
  const int lc = lane & 15;
  const int kfrag = (lane >> 4) * 8;

  f32x4 acc[4][4];
#pragma unroll
  for (int m = 0; m < 4; ++m)
#pragma unroll
    for (int n = 0; n < 4; ++n)
      acc[m][n] = (f32x4){0.f, 0.f, 0.f, 0.f};

  const int srow = tid >> 1;            // A row index / B col index
  const int skoff = (tid & 1) * 16;     // k sub-offset
  const int tok = tokL[srow];
  const float* arow = x + (size_t)tok * HID + skoff;
  const float* bbase = w1 + (size_t)e * HID * FFN + (size_t)jcol * BN + srow;

  float4 a0, a1, a2, a3;
  float bv[16];
  {
    const float4* ap = reinterpret_cast<const float4*>(arow);
    a0 = ap[0]; a1 = ap[1]; a2 = ap[2]; a3 = ap[3];
    const float* bp = bbase + (size_t)skoff * FFN;
#pragma unroll
    for (int i = 0; i < 16; ++i) bv[i] = bp[(size_t)i * FFN];
  }

  for (int kk = 0; kk < HID; kk += BK) {
    __syncthreads();
    uint4* adst = reinterpret_cast<uint4*>(&Asm[srow][skoff]);
    adst[0] = (uint4){pack2(a0.x,a0.y), pack2(a0.z,a0.w), pack2(a1.x,a1.y), pack2(a1.z,a1.w)};
    adst[1] = (uint4){pack2(a2.x,a2.y), pack2(a2.z,a2.w), pack2(a3.x,a3.y), pack2(a3.z,a3.w)};
    uint4* bdst = reinterpret_cast<uint4*>(&Bsm[srow][skoff]);
    bdst[0] = (uint4){pack2(bv[0],bv[1]), pack2(bv[2],bv[3]), pack2(bv[4],bv[5]), pack2(bv[6],bv[7])};
    bdst[1] = (uint4){pack2(bv[8],bv[9]), pack2(bv[10],bv[11]), pack2(bv[12],bv[13]), pack2(bv[14],bv[15])};
    __syncthreads();

    if (kk + BK < HID) {                 // prefetch next K-tile; latency hides under MFMA below
      const float4* ap = reinterpret_cast<const float4*>(arow + kk + BK);
      a0 = ap[0]; a1 = ap[1]; a2 = ap[2]; a3 = ap[3];
      const float* bp = bbase + (size_t)(kk + BK + skoff) * FFN;
#pragma unroll
      for (int i = 0; i < 16; ++i) bv[i] = bp[(size_t)i * FFN];
    }

    half8 af[4], bf[4];
#pragma unroll
    for (int m = 0; m < 4; ++m)
      af[m] = *reinterpret_cast<const half8*>(&Asm[wr + m*16 + lc][kfrag]);
#pragma unroll
    for (int n = 0; n < 4; ++n)
      bf[n] = *reinterpret_cast<const half8*>(&Bsm[wc + n*16 + lc][kfrag]);
#pragma unroll
    for (int m = 0; m < 4; ++m)
#pragma unroll
      for (int n = 0; n < 4; ++n)
        acc[m][n] = __builtin_amdgcn_mfma_f32_16x16x32_f16(af[m], bf[n], acc[m][n], 0, 0, 0);
  }

#pragma unroll
  for (int m = 0; m < 4; ++m) {
#pragma unroll
    for (int r = 0; r < 4; ++r) {
      const int rl = rloc0 + wr + m*16 + lr + r;
      if (rl >= cnt) continue;
      unsigned short* hp = hbuf + (size_t)(rb + wr + m*16 + lr + r) * FFN + jcol*BN + wc + lc;
#pragma unroll
      for (int n = 0; n < 4; ++n) {
        float v = acc[m][n][r];
        float g = 0.5f * v * (1.f + erff(v * 0.70710678118f));   // exact erf-gelu
        hp[n*16] = f2h_bits(g);
      }
    }
  }
}

// ---------------- GEMM2: out[tok] += p * (h @ w2[e]), split-K x2 ----------------
__global__ __launch_bounds__(256) void moe_gemm2(
    const unsigned short* __restrict__ hbuf, const float* __restrict__ w2,
    const int* __restrict__ counts, const int* __restrict__ seg,
    const int* __restrict__ lists, const float* __restrict__ probs,
    float* __restrict__ out)
{
  const int tile = blockIdx.x >> 4;            // [tile][jcol(3b)][ks(1b)]
  const int jcol = (blockIdx.x >> 1) & 7;      // HID/BN = 8 col tiles
  const int ks   = blockIdx.x & 1;             // split-K half
  const int rb = tile * BM;
  if (rb >= seg[NEXP]) return;
  int e = 0;
#pragma unroll
  for (int q = 1; q < NEXP; ++q) if (seg[q] <= rb) e = q;
  const int cnt = counts[e];
  const int rloc0 = rb - seg[e];
  const int k0 = ks * (FFN / 2);
  const int k1 = k0 + (FFN / 2);

  __shared__ int tokL[BM];
  __shared__ float pL[BM];
  __shared__ unsigned short Asm[BM][LDA];
  __shared__ unsigned short Bsm[BN][LDA];

  const int tid = threadIdx.x;
  if (tid < BM) {
    int rl = rloc0 + tid;
    if (rl < cnt) {
      int tk = lists[e * NTOK + rl];
      tokL[tid] = tk;
      pL[tid] = probs[tk * NEXP + e];
    } else { tokL[tid] = 0; pL[tid] = 0.f; }
  }
  __syncthreads();

  const int lane = tid & 63;
  const int wid = tid >> 6;
  const int wr = (wid >> 1) * 64;
  const int wc = (wid & 1) * 64;
  const int lr = (lane >> 4) * 4;
  const int lc = lane & 15;
  const int kfrag = (lane >> 4) * 8;

  f32x4 acc[4][4];
#pragma unroll
  for (int m = 0; m < 4; ++m)
#pragma unroll
    for (int n = 0; n < 4; ++n)
      acc[m][n] = (f32x4){0.f, 0.f, 0.f, 0.f};

  const int srow = tid >> 1;
  const int skoff = (tid & 1) * 16;
  const float* bbase = w2 + (size_t)e * FFN * HID + (size_t)jcol * BN + srow;
  const unsigned short* arow_p = hbuf + (size_t)(rb + srow) * FFN + skoff;

  uint4 av0, av1;
  float bv[16];
  {
    const uint4* ap = reinterpret_cast<const uint4*>(arow_p + k0);
    av0 = ap[0]; av1 = ap[1];
    const float* bp = bbase + (size_t)(k0 + skoff) * HID;
#pragma unroll
    for (int i = 0; i < 16; ++i) bv[i] = bp[(size_t)i * HID];
  }

  for (int kk = k0; kk < k1; kk += BK) {
    __syncthreads();
    uint4* adst = reinterpret_cast<uint4*>(&Asm[srow][skoff]);
    adst[0] = av0; adst[1] = av1;
    uint4* bdst = reinterpret_cast<uint4*>(&Bsm[srow][skoff]);
    bdst[0] = (uint4){pack2(bv[0],bv[1]), pack2(bv[2],bv[3]), pack2(bv[4],bv[5]), pack2(bv[6],bv[7])};
    bdst[1] = (uint4){pack2(bv[8],bv[9]), pack2(bv[10],bv[11]), pack2(bv[12],bv[13]), pack2(bv[14],bv[15])};
    __syncthreads();

    if (kk + BK < k1) {                  // prefetch next K-tile
      const uint4* ap = reinterpret_cast<const uint4*>(arow_p + kk + BK);
      av0 = ap[0]; av1 = ap[1];
      const float* bp = bbase + (size_t)(kk + BK + skoff) * HID;
#pragma unroll
      for (int i = 0; i < 16; ++i) bv[i] = bp[(size_t)i * HID];
    }

    half8 af[4], bf[4];
#pragma unroll
    for (int m = 0; m < 4; ++m)
      af[m] = *reinterpret_cast<const half8*>(&Asm[wr + m*16 + lc][kfrag]);
#pragma unroll
    for (int n = 0; n < 4; ++n)
      bf[n] = *reinterpret_cast<const half8*>(&Bsm[wc + n*16 + lc][kfrag]);
#pragma unroll
    for (int m = 0; m < 4; ++m)
#pragma unroll
      for (int n = 0; n < 4; ++n)
        acc[m][n] = __builtin_amdgcn_mfma_f32_16x16x32_f16(af[m], bf[n], acc[m][n], 0, 0, 0);
  }

#pragma unroll
  for (int m = 0; m < 4; ++m) {
#pragma unroll
    for (int r = 0; r < 4; ++r) {
      const int lrow = wr + m*16 + lr + r;
      const int rl = rloc0 + lrow;
      if (rl >= cnt) continue;
      const int tok = tokL[lrow];
      const float p = pL[lrow];
      float* op = out + (size_t)tok * HID + jcol*BN + wc + lc;
#pragma unroll
      for (int n = 0; n < 4; ++n)
        atomicAdd(&op[n*16], p * acc[m][n][r]);   // <=4 commutative fp32 adds/element
    }
  }
}

extern "C" void kernel_launch(void* const* d_in, const int* in_sizes, int n_in,
                              void* d_out, int out_size, void* d_ws, size_t ws_size,
                              hipStream_t stream) {
  const float* x  = (const float*)d_in[0];
  const float* rw = (const float*)d_in[1];
  const float* w1 = (const float*)d_in[2];
  const float* w2 = (const float*)d_in[3];
  float* out = (float*)d_out;

  char* ws = (char*)d_ws;
  int*   counts = (int*)(ws + WS_COUNTS);
  int*   seg    = (int*)(ws + WS_SEG);
  float* probs  = (float*)(ws + WS_PROBS);
  int*   lists  = (int*)(ws + WS_LISTS);
  unsigned short* hbuf = (unsigned short*)(ws + WS_HBUF);

  hipMemsetAsync(ws, 0, 128, stream);                                   // counts
  hipMemsetAsync(d_out, 0, (size_t)NTOK * HID * sizeof(float), stream); // atomic target

  moe_router<<<NTOK, 64, 0, stream>>>(x, rw, counts, lists, probs);
  moe_segoff<<<1, 64, 0, stream>>>(counts, seg);
  moe_gemm1<<<MAX_TILES * (FFN / BN), 256, 0, stream>>>(x, w1, counts, seg, lists, hbuf);
  moe_gemm2<<<MAX_TILES * (HID / BN) * 2, 256, 0, stream>>>(hbuf, w2, counts, seg, lists, probs, out);
}

// Round 3
// 224.049 us; speedup vs baseline: 1.1136x; 1.0857x over previous
//
#include <hip/hip_runtime.h>
#include <hip/hip_fp16.h>
#include <math.h>

#define NTOK 2048
#define HID  1024
#define FFN  2048
#define NEXP 8

#define BM 128
#define BN 128
#define BK 64             // fp16 K-step per LDS tile
#define MAX_TILES 40      // sum ceil(cnt_e/BM) <= 4096/128 + 7 = 39

// workspace layout (bytes)
#define WS_COUNTS 0                         // 8 ints (zeroed each launch)
#define WS_SEG    32                        // 9 ints
#define WS_PROBS  128                       // NTOK*NEXP floats = 64KB
#define WS_LISTS  (128 + NTOK*NEXP*4)       // 8*NTOK ints = 64KB
#define WS_XH     262144                    // [NTOK][HID] fp16 = 4MB
#define WS_W1T    (WS_XH + NTOK*HID*2)      // [E][F][H] fp16 = 32MB
#define WS_W2T    (WS_W1T + NEXP*HID*FFN*2) // [E][H][F] fp16 = 32MB
#define WS_HBUF   (WS_W2T + NEXP*HID*FFN*2) // [5120][FFN] fp16 = 20MB  (total ~88.3MB)

typedef _Float16 half8 __attribute__((ext_vector_type(8)));
typedef float    f32x4 __attribute__((ext_vector_type(4)));

static __device__ __forceinline__ unsigned short f2h_bits(float f) {
  union { _Float16 h; unsigned short u; } v;
  v.h = (_Float16)f;
  return v.u;
}
static __device__ __forceinline__ unsigned pack2(float a, float b) {
  return (unsigned)f2h_bits(a) | ((unsigned)f2h_bits(b) << 16);
}

#define GLOAD16(gsrc, ldst) \
  __builtin_amdgcn_global_load_lds( \
      (const __attribute__((address_space(1))) unsigned int*)(gsrc), \
      (__attribute__((address_space(3))) unsigned int*)(ldst), 16, 0, 0)

// ---------------- x fp32 -> fp16 ----------------
__global__ __launch_bounds__(256) void convert_x(
    const float* __restrict__ x, unsigned short* __restrict__ xh)
{
  const size_t i = ((size_t)blockIdx.x * 256 + threadIdx.x) * 8;
  const float4* src = reinterpret_cast<const float4*>(x + i);
  float4 v0 = src[0], v1 = src[1];
  uint4 p = {pack2(v0.x,v0.y), pack2(v0.z,v0.w), pack2(v1.x,v1.y), pack2(v1.z,v1.w)};
  *reinterpret_cast<uint4*>(xh + i) = p;
}

// ---------------- per-expert transpose + fp16 convert: in [E][R][C] -> out [E][C][R] ----------------
__global__ __launch_bounds__(256) void transpose_cvt(
    const float* __restrict__ in, unsigned short* __restrict__ out, int R, int C)
{
  const int e  = blockIdx.z;
  const int c0 = blockIdx.x * 64;
  const int r0 = blockIdx.y * 64;
  const float* ine = in + (size_t)e * R * C;
  unsigned short* oute = out + (size_t)e * R * C;
  __shared__ unsigned short Ls[64][72];     // pad 8 halfwords
  const int tid = threadIdx.x;
  {
    const int r = tid >> 2, cq = tid & 3;
    const float4* src = reinterpret_cast<const float4*>(ine + (size_t)(r0 + r) * C + c0 + cq*16);
    float4 v0 = src[0], v1 = src[1], v2 = src[2], v3 = src[3];
    *reinterpret_cast<uint4*>(&Ls[r][cq*16]) =
        (uint4){pack2(v0.x,v0.y), pack2(v0.z,v0.w), pack2(v1.x,v1.y), pack2(v1.z,v1.w)};
    *reinterpret_cast<uint4*>(&Ls[r][cq*16+8]) =
        (uint4){pack2(v2.x,v2.y), pack2(v2.z,v2.w), pack2(v3.x,v3.y), pack2(v3.z,v3.w)};
  }
  __syncthreads();
  {
    const int oc = tid >> 2, rq = tid & 3;
    unsigned v[8];
#pragma unroll
    for (int j = 0; j < 8; ++j) {
      unsigned lo = Ls[rq*16 + 2*j][oc];
      unsigned hi = Ls[rq*16 + 2*j + 1][oc];
      v[j] = lo | (hi << 16);
    }
    unsigned short* dst = oute + (size_t)(c0 + oc) * R + r0 + rq*16;
    *reinterpret_cast<uint4*>(dst)     = (uint4){v[0],v[1],v[2],v[3]};
    *reinterpret_cast<uint4*>(dst + 8) = (uint4){v[4],v[5],v[6],v[7]};
  }
}

// ---------------- router: logits -> softmax -> top2 -> scatter ----------------
__global__ __launch_bounds__(64) void moe_router(
    const float* __restrict__ x, const float* __restrict__ rw,
    int* __restrict__ counts, int* __restrict__ lists, float* __restrict__ probs)
{
  const int t = blockIdx.x;
  const int lane = threadIdx.x;
  const float* xr = x + (size_t)t * HID;

  float acc[NEXP];
#pragma unroll
  for (int e = 0; e < NEXP; ++e) acc[e] = 0.f;

  for (int h = lane; h < HID; h += 64) {
    float xv = xr[h];
    const float4* rp = reinterpret_cast<const float4*>(rw + (size_t)h * NEXP);
    float4 a = rp[0], b = rp[1];
    acc[0] += xv * a.x; acc[1] += xv * a.y; acc[2] += xv * a.z; acc[3] += xv * a.w;
    acc[4] += xv * b.x; acc[5] += xv * b.y; acc[6] += xv * b.z; acc[7] += xv * b.w;
  }
#pragma unroll
  for (int off = 32; off > 0; off >>= 1) {
#pragma unroll
    for (int e = 0; e < NEXP; ++e) acc[e] += __shfl_down(acc[e], off);
  }

  if (lane == 0) {
    float m = acc[0];
#pragma unroll
    for (int e = 1; e < NEXP; ++e) m = fmaxf(m, acc[e]);
    float p[NEXP];
#pragma unroll
    for (int e = 0; e < NEXP; ++e) p[e] = expf(acc[e] - m);
    int i0 = 0;
#pragma unroll
    for (int e = 1; e < NEXP; ++e) if (p[e] > p[i0]) i0 = e;
    int i1 = -1;
#pragma unroll
    for (int e = 0; e < NEXP; ++e) {
      if (e == i0) continue;
      if (i1 < 0 || p[e] > p[i1]) i1 = e;
    }
    const float inv = 1.f / (p[i0] + p[i1]);
    probs[t * NEXP + i0] = p[i0] * inv;
    probs[t * NEXP + i1] = p[i1] * inv;
    int pos0 = atomicAdd(&counts[i0], 1); lists[i0 * NTOK + pos0] = t;
    int pos1 = atomicAdd(&counts[i1], 1); lists[i1 * NTOK + pos1] = t;
  }
}

// ---------------- padded segment offsets ----------------
__global__ void moe_segoff(const int* __restrict__ counts, int* __restrict__ seg) {
  if (threadIdx.x == 0 && blockIdx.x == 0) {
    int run = 0;
    for (int e = 0; e < NEXP; ++e) {
      seg[e] = run;
      run += ((counts[e] + BM - 1) / BM) * BM;
    }
    seg[NEXP] = run;
  }
}

// ---------------- GEMM1: h = gelu(xh[tok] @ w1t[e]^T) -> fp16 hbuf ----------------
// A,B both fp16 K-contiguous rows; staged via global_load_lds w16; 2-phase dbuf.
__global__ __launch_bounds__(256) void moe_gemm1(
    const unsigned short* __restrict__ xh, const unsigned short* __restrict__ w1t,
    const int* __restrict__ counts, const int* __restrict__ seg,
    const int* __restrict__ lists, unsigned short* __restrict__ hbuf)
{
  const int tile = blockIdx.x >> 4;     // FFN/BN = 16 col tiles
  const int jcol = blockIdx.x & 15;
  const int rb = tile * BM;
  if (rb >= seg[NEXP]) return;
  int e = 0;
#pragma unroll
  for (int q = 1; q < NEXP; ++q) if (seg[q] <= rb) e = q;
  const int cnt = counts[e];
  const int rloc0 = rb - seg[e];

  __shared__ int tokL[BM];
  __shared__ unsigned short Asm[2][BM*BK];   // 16KB each
  __shared__ unsigned short Bsm[2][BM*BK];

  const int tid = threadIdx.x;
  if (tid < BM) {
    int rl = rloc0 + tid;
    tokL[tid] = (rl < cnt) ? lists[e * NTOK + rl] : 0;
  }
  __syncthreads();

  const int lane = tid & 63;
  const int wid = tid >> 6;
  const int wr = (wid >> 1) * 64;
  const int wc = (wid & 1) * 64;
  const int lr = (lane >> 4) * 4;
  const int lc = lane & 15;
  const int khi = (lane >> 4) * 8;

  // staging geometry: chunk = b*256 + wid*64 + lane; row = chunk>>3; cw = lane&7
  const int cw = lane & 7;
  const unsigned short* abase[4];
  const unsigned short* bbase[4];
#pragma unroll
  for (int b = 0; b < 4; ++b) {
    const int row = b*32 + wid*8 + (lane >> 3);
    abase[b] = xh + (size_t)tokL[row] * HID + cw*8;
    bbase[b] = w1t + ((size_t)e * FFN + jcol*BN + row) * HID + cw*8;
  }

  f32x4 acc[4][4];
#pragma unroll
  for (int m = 0; m < 4; ++m)
#pragma unroll
    for (int n = 0; n < 4; ++n)
      acc[m][n] = (f32x4){0.f, 0.f, 0.f, 0.f};

#define STAGE1(buf, kk) do { \
    _Pragma("unroll") \
    for (int b = 0; b < 4; ++b) { \
      GLOAD16(abase[b] + (kk), &Asm[buf][(b*256 + wid*64)*8]); \
      GLOAD16(bbase[b] + (kk), &Bsm[buf][(b*256 + wid*64)*8]); \
    } } while (0)

  STAGE1(0, 0);
  __syncthreads();
  int cur = 0;
  for (int kk = 0; kk < HID; kk += BK) {
    if (kk + BK < HID) STAGE1(cur ^ 1, kk + BK);
#pragma unroll
    for (int kh = 0; kh < 2; ++kh) {
      half8 af[4], bf[4];
#pragma unroll
      for (int m = 0; m < 4; ++m)
        af[m] = *reinterpret_cast<const half8*>(&Asm[cur][(wr + m*16 + lc)*BK + kh*32 + khi]);
#pragma unroll
      for (int n = 0; n < 4; ++n)
        bf[n] = *reinterpret_cast<const half8*>(&Bsm[cur][(wc + n*16 + lc)*BK + kh*32 + khi]);
#pragma unroll
      for (int m = 0; m < 4; ++m)
#pragma unroll
        for (int n = 0; n < 4; ++n)
          acc[m][n] = __builtin_amdgcn_mfma_f32_16x16x32_f16(af[m], bf[n], acc[m][n], 0, 0, 0);
    }
    __syncthreads();
    cur ^= 1;
  }
#undef STAGE1

#pragma unroll
  for (int m = 0; m < 4; ++m) {
#pragma unroll
    for (int r = 0; r < 4; ++r) {
      const int rl = rloc0 + wr + m*16 + lr + r;
      if (rl >= cnt) continue;
      unsigned short* hp = hbuf + (size_t)(rb + wr + m*16 + lr + r) * FFN + jcol*BN + wc + lc;
#pragma unroll
      for (int n = 0; n < 4; ++n) {
        float v = acc[m][n][r];
        float g = 0.5f * v * (1.f + erff(v * 0.70710678118f));   // exact erf-gelu
        hp[n*16] = f2h_bits(g);
      }
    }
  }
}

// ---------------- GEMM2: out[tok] += p * (hbuf @ w2t[e]^T), split-K x2 ----------------
__global__ __launch_bounds__(256) void moe_gemm2(
    const unsigned short* __restrict__ hbuf, const unsigned short* __restrict__ w2t,
    const int* __restrict__ counts, const int* __restrict__ seg,
    const int* __restrict__ lists, const float* __restrict__ probs,
    float* __restrict__ out)
{
  const int tile = blockIdx.x >> 4;            // [tile][jcol(3b)][ks(1b)]
  const int jcol = (blockIdx.x >> 1) & 7;      // HID/BN = 8 col tiles
  const int ks   = blockIdx.x & 1;
  const int rb = tile * BM;
  if (rb >= seg[NEXP]) return;
  int e = 0;
#pragma unroll
  for (int q = 1; q < NEXP; ++q) if (seg[q] <= rb) e = q;
  const int cnt = counts[e];
  const int rloc0 = rb - seg[e];
  const int k0 = ks * (FFN / 2);
  const int k1 = k0 + (FFN / 2);

  __shared__ int tokL[BM];
  __shared__ float pL[BM];
  __shared__ unsigned short Asm[2][BM*BK];
  __shared__ unsigned short Bsm[2][BM*BK];

  const int tid = threadIdx.x;
  if (tid < BM) {
    int rl = rloc0 + tid;
    if (rl < cnt) {
      int tk = lists[e * NTOK + rl];
      tokL[tid] = tk;
      pL[tid] = probs[tk * NEXP + e];
    } else { tokL[tid] = 0; pL[tid] = 0.f; }
  }
  __syncthreads();

  const int lane = tid & 63;
  const int wid = tid >> 6;
  const int wr = (wid >> 1) * 64;
  const int wc = (wid & 1) * 64;
  const int lr = (lane >> 4) * 4;
  const int lc = lane & 15;
  const int khi = (lane >> 4) * 8;

  const int cw = lane & 7;
  const unsigned short* abase[4];
  const unsigned short* bbase[4];
#pragma unroll
  for (int b = 0; b < 4; ++b) {
    const int row = b*32 + wid*8 + (lane >> 3);
    abase[b] = hbuf + (size_t)(rb + row) * FFN + cw*8;
    bbase[b] = w2t + ((size_t)e * HID + jcol*BN + row) * FFN + cw*8;
  }

  f32x4 acc[4][4];
#pragma unroll
  for (int m = 0; m < 4; ++m)
#pragma unroll
    for (int n = 0; n < 4; ++n)
      acc[m][n] = (f32x4){0.f, 0.f, 0.f, 0.f};

#define STAGE2(buf, kk) do { \
    _Pragma("unroll") \
    for (int b = 0; b < 4; ++b) { \
      GLOAD16(abase[b] + (kk), &Asm[buf][(b*256 + wid*64)*8]); \
      GLOAD16(bbase[b] + (kk), &Bsm[buf][(b*256 + wid*64)*8]); \
    } } while (0)

  STAGE2(0, k0);
  __syncthreads();
  int cur = 0;
  for (int kk = k0; kk < k1; kk += BK) {
    if (kk + BK < k1) STAGE2(cur ^ 1, kk + BK);
#pragma unroll
    for (int kh = 0; kh < 2; ++kh) {
      half8 af[4], bf[4];
#pragma unroll
      for (int m = 0; m < 4; ++m)
        af[m] = *reinterpret_cast<const half8*>(&Asm[cur][(wr + m*16 + lc)*BK + kh*32 + khi]);
#pragma unroll
      for (int n = 0; n < 4; ++n)
        bf[n] = *reinterpret_cast<const half8*>(&Bsm[cur][(wc + n*16 + lc)*BK + kh*32 + khi]);
#pragma unroll
      for (int m = 0; m < 4; ++m)
#pragma unroll
        for (int n = 0; n < 4; ++n)
          acc[m][n] = __builtin_amdgcn_mfma_f32_16x16x32_f16(af[m], bf[n], acc[m][n], 0, 0, 0);
    }
    __syncthreads();
    cur ^= 1;
  }
#undef STAGE2

#pragma unroll
  for (int m = 0; m < 4; ++m) {
#pragma unroll
    for (int r = 0; r < 4; ++r) {
      const int lrow = wr + m*16 + lr + r;
      const int rl = rloc0 + lrow;
      if (rl >= cnt) continue;
      const int tok = tokL[lrow];
      const float p = pL[lrow];
      float* op = out + (size_t)tok * HID + jcol*BN + wc + lc;
#pragma unroll
      for (int n = 0; n < 4; ++n)
        atomicAdd(&op[n*16], p * acc[m][n][r]);   // <=4 commutative fp32 adds/element
    }
  }
}

extern "C" void kernel_launch(void* const* d_in, const int* in_sizes, int n_in,
                              void* d_out, int out_size, void* d_ws, size_t ws_size,
                              hipStream_t stream) {
  const float* x  = (const float*)d_in[0];
  const float* rw = (const float*)d_in[1];
  const float* w1 = (const float*)d_in[2];
  const float* w2 = (const float*)d_in[3];
  float* out = (float*)d_out;

  char* ws = (char*)d_ws;
  int*   counts = (int*)(ws + WS_COUNTS);
  int*   seg    = (int*)(ws + WS_SEG);
  float* probs  = (float*)(ws + WS_PROBS);
  int*   lists  = (int*)(ws + WS_LISTS);
  unsigned short* xh   = (unsigned short*)(ws + WS_XH);
  unsigned short* w1t  = (unsigned short*)(ws + WS_W1T);
  unsigned short* w2t  = (unsigned short*)(ws + WS_W2T);
  unsigned short* hbuf = (unsigned short*)(ws + WS_HBUF);

  hipMemsetAsync(ws, 0, 128, stream);                                   // counts
  hipMemsetAsync(d_out, 0, (size_t)NTOK * HID * sizeof(float), stream); // atomic target

  convert_x<<<NTOK * HID / (256 * 8), 256, 0, stream>>>(x, xh);
  transpose_cvt<<<dim3(FFN/64, HID/64, NEXP), 256, 0, stream>>>(w1, w1t, HID, FFN);
  transpose_cvt<<<dim3(HID/64, FFN/64, NEXP), 256, 0, stream>>>(w2, w2t, FFN, HID);
  moe_router<<<NTOK, 64, 0, stream>>>(x, rw, counts, lists, probs);
  moe_segoff<<<1, 64, 0, stream>>>(counts, seg);
  moe_gemm1<<<MAX_TILES * (FFN / BN), 256, 0, stream>>>(xh, w1t, counts, seg, lists, hbuf);
  moe_gemm2<<<MAX_TILES * (HID / BN) * 2, 256, 0, stream>>>(hbuf, w2t, counts, seg, lists, probs, out);
}

// Round 5
// 191.756 us; speedup vs baseline: 1.3011x; 1.1684x over previous
//
#include <hip/hip_runtime.h>
#include <hip/hip_fp16.h>
#include <math.h>

#define NTOK 2048
#define HID  1024
#define FFN  2048
#define NEXP 8

#define BM 128
#define BN 128
#define BK 32             // fp16 K-step; LDS = 33KB/block -> 4 blocks/CU
#define MAX_TILES 40

// workspace layout (bytes)
#define WS_COUNTS 0
#define WS_SEG    32
#define WS_PROBS  128                       // NTOK*NEXP floats = 64KB
#define WS_LISTS  (128 + NTOK*NEXP*4)       // 8*NTOK ints = 64KB
#define WS_XH     262144                    // [NTOK][HID] fp16 = 4MB
#define WS_W1T    (WS_XH + NTOK*HID*2)      // [E][F][H] fp16 = 32MB
#define WS_W2T    (WS_W1T + NEXP*HID*FFN*2) // [E][H][F] fp16 = 32MB
#define WS_HBUF   (WS_W2T + NEXP*HID*FFN*2) // [5120][FFN] fp16 = 20MB

typedef _Float16 half8 __attribute__((ext_vector_type(8)));
typedef float    f32x4 __attribute__((ext_vector_type(4)));

static __device__ __forceinline__ unsigned short f2h_bits(float f) {
  union { _Float16 h; unsigned short u; } v;
  v.h = (_Float16)f;
  return v.u;
}
static __device__ __forceinline__ unsigned pack2(float a, float b) {
  return (unsigned)f2h_bits(a) | ((unsigned)f2h_bits(b) << 16);
}

#define GLOAD16(gsrc, ldst) \
  __builtin_amdgcn_global_load_lds( \
      (const __attribute__((address_space(1))) unsigned int*)(gsrc), \
      (__attribute__((address_space(3))) unsigned int*)(ldst), 16, 0, 0)

// Drain all outstanding global_load_lds DMA writes issued by this wave.
// Do NOT rely on the compiler emitting vmcnt(0) before s_barrier (T3 recipe
// writes it explicitly; round-4 post-timing divergence fits a missing drain).
#define VMCNT0 asm volatile("s_waitcnt vmcnt(0)" ::: "memory")

// ---------------- fused prep: w1 transpose | w2 transpose | router + x->fp16 ----------------
// blocks [0,4096): w1 [E][H][F] -> w1t [E][F][H] fp16
// blocks [4096,8192): w2 [E][F][H] -> w2t [E][H][F] fp16
// blocks [8192,8704): router (4 tokens/block, 1 wave each) + xh write
__global__ __launch_bounds__(256) void moe_prep(
    const float* __restrict__ x, const float* __restrict__ rw,
    const float* __restrict__ w1, const float* __restrict__ w2,
    unsigned short* __restrict__ xh, unsigned short* __restrict__ w1t,
    unsigned short* __restrict__ w2t,
    int* __restrict__ counts, int* __restrict__ lists, float* __restrict__ probs)
{
  __shared__ unsigned short Ls[64][72];
  const int bid = blockIdx.x;
  const int tid = threadIdx.x;

  if (bid < 8192) {
    const float* in; unsigned short* out; int C, R, r0, c0;
    if (bid < 4096) {
      const int e = bid >> 9, rem = bid & 511;
      in = w1 + (size_t)e * HID * FFN; out = w1t + (size_t)e * HID * FFN;
      R = HID; C = FFN; c0 = (rem & 31) * 64; r0 = (rem >> 5) * 64;
    } else {
      const int b = bid - 4096, e = b >> 9, rem = b & 511;
      in = w2 + (size_t)e * HID * FFN; out = w2t + (size_t)e * HID * FFN;
      R = FFN; C = HID; c0 = (rem & 15) * 64; r0 = (rem >> 4) * 64;
    }
    {
      const int r = tid >> 2, cq = tid & 3;
      const float4* src = reinterpret_cast<const float4*>(in + (size_t)(r0 + r) * C + c0 + cq*16);
      float4 v0 = src[0], v1 = src[1], v2 = src[2], v3 = src[3];
      *reinterpret_cast<uint4*>(&Ls[r][cq*16]) =
          (uint4){pack2(v0.x,v0.y), pack2(v0.z,v0.w), pack2(v1.x,v1.y), pack2(v1.z,v1.w)};
      *reinterpret_cast<uint4*>(&Ls[r][cq*16+8]) =
          (uint4){pack2(v2.x,v2.y), pack2(v2.z,v2.w), pack2(v3.x,v3.y), pack2(v3.z,v3.w)};
    }
    __syncthreads();
    {
      const int oc = tid >> 2, rq = tid & 3;
      unsigned v[8];
#pragma unroll
      for (int j = 0; j < 8; ++j) {
        unsigned lo = Ls[rq*16 + 2*j][oc];
        unsigned hi = Ls[rq*16 + 2*j + 1][oc];
        v[j] = lo | (hi << 16);
      }
      unsigned short* dst = out + (size_t)(c0 + oc) * R + r0 + rq*16;
      *reinterpret_cast<uint4*>(dst)     = (uint4){v[0],v[1],v[2],v[3]};
      *reinterpret_cast<uint4*>(dst + 8) = (uint4){v[4],v[5],v[6],v[7]};
    }
  } else {
    const int wid = tid >> 6, lane = tid & 63;
    const int t = (bid - 8192) * 4 + wid;
    const float* xr = x + (size_t)t * HID + lane * 16;
    const float4* xp = reinterpret_cast<const float4*>(xr);
    float4 v0 = xp[0], v1 = xp[1], v2 = xp[2], v3 = xp[3];
    float xv[16] = {v0.x,v0.y,v0.z,v0.w, v1.x,v1.y,v1.z,v1.w,
                    v2.x,v2.y,v2.z,v2.w, v3.x,v3.y,v3.z,v3.w};
    float acc[NEXP];
#pragma unroll
    for (int e = 0; e < NEXP; ++e) acc[e] = 0.f;
#pragma unroll
    for (int j = 0; j < 16; ++j) {
      const float4* rp = reinterpret_cast<const float4*>(rw + (size_t)(lane*16 + j) * NEXP);
      float4 a = rp[0], b = rp[1];
      acc[0] += xv[j]*a.x; acc[1] += xv[j]*a.y; acc[2] += xv[j]*a.z; acc[3] += xv[j]*a.w;
      acc[4] += xv[j]*b.x; acc[5] += xv[j]*b.y; acc[6] += xv[j]*b.z; acc[7] += xv[j]*b.w;
    }
#pragma unroll
    for (int off = 32; off > 0; off >>= 1) {
#pragma unroll
      for (int e = 0; e < NEXP; ++e) acc[e] += __shfl_down(acc[e], off);
    }
    // xh write (each lane owns 16 contiguous elements)
    unsigned short* xd = xh + (size_t)t * HID + lane * 16;
    *reinterpret_cast<uint4*>(xd) =
        (uint4){pack2(v0.x,v0.y), pack2(v0.z,v0.w), pack2(v1.x,v1.y), pack2(v1.z,v1.w)};
    *reinterpret_cast<uint4*>(xd + 8) =
        (uint4){pack2(v2.x,v2.y), pack2(v2.z,v2.w), pack2(v3.x,v3.y), pack2(v3.z,v3.w)};
    if (lane == 0) {
      float m = acc[0];
#pragma unroll
      for (int e = 1; e < NEXP; ++e) m = fmaxf(m, acc[e]);
      float p[NEXP];
#pragma unroll
      for (int e = 0; e < NEXP; ++e) p[e] = expf(acc[e] - m);
      int i0 = 0;
#pragma unroll
      for (int e = 1; e < NEXP; ++e) if (p[e] > p[i0]) i0 = e;
      int i1 = -1;
#pragma unroll
      for (int e = 0; e < NEXP; ++e) {
        if (e == i0) continue;
        if (i1 < 0 || p[e] > p[i1]) i1 = e;
      }
      const float inv = 1.f / (p[i0] + p[i1]);
      probs[t * NEXP + i0] = p[i0] * inv;
      probs[t * NEXP + i1] = p[i1] * inv;
      int pos0 = atomicAdd(&counts[i0], 1); lists[i0 * NTOK + pos0] = t;
      int pos1 = atomicAdd(&counts[i1], 1); lists[i1 * NTOK + pos1] = t;
    }
  }
}

// ---------------- padded segment offsets ----------------
__global__ void moe_segoff(const int* __restrict__ counts, int* __restrict__ seg) {
  if (threadIdx.x == 0 && blockIdx.x == 0) {
    int run = 0;
    for (int e = 0; e < NEXP; ++e) {
      seg[e] = run;
      run += ((counts[e] + BM - 1) / BM) * BM;
    }
    seg[NEXP] = run;
  }
}

// ---------------- GEMM1: h = gelu(xh[tok] @ w1t[e]^T) -> fp16 hbuf ----------------
__global__ __launch_bounds__(256) void moe_gemm1(
    const unsigned short* __restrict__ xh, const unsigned short* __restrict__ w1t,
    const int* __restrict__ counts, const int* __restrict__ seg,
    const int* __restrict__ lists, unsigned short* __restrict__ hbuf)
{
  const int tile = blockIdx.x >> 4;
  const int jcol = blockIdx.x & 15;
  const int rb = tile * BM;
  if (rb >= seg[NEXP]) return;
  int e = 0;
#pragma unroll
  for (int q = 1; q < NEXP; ++q) if (seg[q] <= rb) e = q;
  const int cnt = counts[e];
  const int rloc0 = rb - seg[e];

  __shared__ int tokL[BM];
  __shared__ __align__(16) unsigned short Asm[2][BM*BK];   // 8KB per buffer
  __shared__ __align__(16) unsigned short Bsm[2][BM*BK];

  const int tid = threadIdx.x;
  if (tid < BM) {
    int rl = rloc0 + tid;
    tokL[tid] = (rl < cnt) ? lists[e * NTOK + rl] : 0;
  }
  __syncthreads();

  const int lane = tid & 63;
  const int wid = tid >> 6;
  const int wr = (wid >> 1) * 64;
  const int wc = (wid & 1) * 64;
  const int lr = (lane >> 4) * 4;
  const int lc = lane & 15;
  const int khi = (lane >> 4) * 8;

  // staging: chunk = i*256 + wid*64 + lane; row = chunk>>2; 16B col = (lane&3)*8 halfwords
  const int cw8 = (lane & 3) * 8;
  const int r0 = wid*16 + (lane >> 2);
  const unsigned short* abase[2];
  const unsigned short* bbase[2];
  abase[0] = xh + (size_t)tokL[r0]      * HID + cw8;
  abase[1] = xh + (size_t)tokL[64 + r0] * HID + cw8;
  bbase[0] = w1t + ((size_t)e * FFN + jcol*BN + r0)      * HID + cw8;
  bbase[1] = w1t + ((size_t)e * FFN + jcol*BN + 64 + r0) * HID + cw8;

  f32x4 acc[4][4];
#pragma unroll
  for (int m = 0; m < 4; ++m)
#pragma unroll
    for (int n = 0; n < 4; ++n)
      acc[m][n] = (f32x4){0.f, 0.f, 0.f, 0.f};

#define STAGE1(buf, kk) do { \
    _Pragma("unroll") \
    for (int i = 0; i < 2; ++i) { \
      GLOAD16(abase[i] + (kk), &Asm[buf][(i*256 + wid*64)*8]); \
      GLOAD16(bbase[i] + (kk), &Bsm[buf][(i*256 + wid*64)*8]); \
    } } while (0)

  STAGE1(0, 0);
  VMCNT0;
  __syncthreads();
  int cur = 0;
  for (int kk = 0; kk < HID; kk += BK) {
    if (kk + BK < HID) STAGE1(cur ^ 1, kk + BK);
    half8 af[4], bf[4];
#pragma unroll
    for (int m = 0; m < 4; ++m)
      af[m] = *reinterpret_cast<const half8*>(&Asm[cur][(wr + m*16 + lc)*BK + khi]);
#pragma unroll
    for (int n = 0; n < 4; ++n)
      bf[n] = *reinterpret_cast<const half8*>(&Bsm[cur][(wc + n*16 + lc)*BK + khi]);
#pragma unroll
    for (int m = 0; m < 4; ++m)
#pragma unroll
      for (int n = 0; n < 4; ++n)
        acc[m][n] = __builtin_amdgcn_mfma_f32_16x16x32_f16(af[m], bf[n], acc[m][n], 0, 0, 0);
    VMCNT0;              // drain next-tile DMA issued above (overlapped with MFMA)
    __syncthreads();
    cur ^= 1;
  }
#undef STAGE1

  // Unconditional writes: padding rows (rl>=cnt) get deterministic values
  // (token-0 data), so gemm2 never reads poison from hbuf.
#pragma unroll
  for (int m = 0; m < 4; ++m) {
#pragma unroll
    for (int r = 0; r < 4; ++r) {
      unsigned short* hp = hbuf + (size_t)(rb + wr + m*16 + lr + r) * FFN + jcol*BN + wc + lc;
#pragma unroll
      for (int n = 0; n < 4; ++n) {
        float v = acc[m][n][r];
        float g = 0.5f * v * (1.f + erff(v * 0.70710678118f));   // exact erf-gelu
        hp[n*16] = f2h_bits(g);
      }
    }
  }
}

// ---------------- GEMM2: out[tok] += p * (hbuf @ w2t[e]^T), split-K x2 ----------------
__global__ __launch_bounds__(256) void moe_gemm2(
    const unsigned short* __restrict__ hbuf, const unsigned short* __restrict__ w2t,
    const int* __restrict__ counts, const int* __restrict__ seg,
    const int* __restrict__ lists, const float* __restrict__ probs,
    float* __restrict__ out)
{
  const int tile = blockIdx.x >> 4;
  const int jcol = (blockIdx.x >> 1) & 7;
  const int ks   = blockIdx.x & 1;
  const int rb = tile * BM;
  if (rb >= seg[NEXP]) return;
  int e = 0;
#pragma unroll
  for (int q = 1; q < NEXP; ++q) if (seg[q] <= rb) e = q;
  const int cnt = counts[e];
  const int rloc0 = rb - seg[e];
  const int k0 = ks * (FFN / 2);
  const int k1 = k0 + (FFN / 2);

  __shared__ int tokL[BM];
  __shared__ float pL[BM];
  __shared__ __align__(16) unsigned short Asm[2][BM*BK];
  __shared__ __align__(16) unsigned short Bsm[2][BM*BK];

  const int tid = threadIdx.x;
  if (tid < BM) {
    int rl = rloc0 + tid;
    if (rl < cnt) {
      int tk = lists[e * NTOK + rl];
      tokL[tid] = tk;
      pL[tid] = probs[tk * NEXP + e];
    } else { tokL[tid] = 0; pL[tid] = 0.f; }
  }
  __syncthreads();

  const int lane = tid & 63;
  const int wid = tid >> 6;
  const int wr = (wid >> 1) * 64;
  const int wc = (wid & 1) * 64;
  const int lr = (lane >> 4) * 4;
  const int lc = lane & 15;
  const int khi = (lane >> 4) * 8;

  const int cw8 = (lane & 3) * 8;
  const int r0 = wid*16 + (lane >> 2);
  const unsigned short* abase[2];
  const unsigned short* bbase[2];
  abase[0] = hbuf + (size_t)(rb + r0)      * FFN + cw8;
  abase[1] = hbuf + (size_t)(rb + 64 + r0) * FFN + cw8;
  bbase[0] = w2t + ((size_t)e * HID + jcol*BN + r0)      * FFN + cw8;
  bbase[1] = w2t + ((size_t)e * HID + jcol*BN + 64 + r0) * FFN + cw8;

  f32x4 acc[4][4];
#pragma unroll
  for (int m = 0; m < 4; ++m)
#pragma unroll
    for (int n = 0; n < 4; ++n)
      acc[m][n] = (f32x4){0.f, 0.f, 0.f, 0.f};

#define STAGE2(buf, kk) do { \
    _Pragma("unroll") \
    for (int i = 0; i < 2; ++i) { \
      GLOAD16(abase[i] + (kk), &Asm[buf][(i*256 + wid*64)*8]); \
      GLOAD16(bbase[i] + (kk), &Bsm[buf][(i*256 + wid*64)*8]); \
    } } while (0)

  STAGE2(0, k0);
  VMCNT0;
  __syncthreads();
  int cur = 0;
  for (int kk = k0; kk < k1; kk += BK) {
    if (kk + BK < k1) STAGE2(cur ^ 1, kk + BK);
    half8 af[4], bf[4];
#pragma unroll
    for (int m = 0; m < 4; ++m)
      af[m] = *reinterpret_cast<const half8*>(&Asm[cur][(wr + m*16 + lc)*BK + khi]);
#pragma unroll
    for (int n = 0; n < 4; ++n)
      bf[n] = *reinterpret_cast<const half8*>(&Bsm[cur][(wc + n*16 + lc)*BK + khi]);
#pragma unroll
    for (int m = 0; m < 4; ++m)
#pragma unroll
      for (int n = 0; n < 4; ++n)
        acc[m][n] = __builtin_amdgcn_mfma_f32_16x16x32_f16(af[m], bf[n], acc[m][n], 0, 0, 0);
    VMCNT0;              // drain next-tile DMA issued above
    __syncthreads();
    cur ^= 1;
  }
#undef STAGE2

#pragma unroll
  for (int m = 0; m < 4; ++m) {
#pragma unroll
    for (int r = 0; r < 4; ++r) {
      const int lrow = wr + m*16 + lr + r;
      const int rl = rloc0 + lrow;
      if (rl >= cnt) continue;
      const int tok = tokL[lrow];
      const float p = pL[lrow];
      float* op = out + (size_t)tok * HID + jcol*BN + wc + lc;
#pragma unroll
      for (int n = 0; n < 4; ++n)
        atomicAdd(&op[n*16], p * acc[m][n][r]);   // <=4 commutative fp32 adds/element
    }
  }
}

extern "C" void kernel_launch(void* const* d_in, const int* in_sizes, int n_in,
                              void* d_out, int out_size, void* d_ws, size_t ws_size,
                              hipStream_t stream) {
  const float* x  = (const float*)d_in[0];
  const float* rw = (const float*)d_in[1];
  const float* w1 = (const float*)d_in[2];
  const float* w2 = (const float*)d_in[3];
  float* out = (float*)d_out;

  char* ws = (char*)d_ws;
  int*   counts = (int*)(ws + WS_COUNTS);
  int*   seg    = (int*)(ws + WS_SEG);
  float* probs  = (float*)(ws + WS_PROBS);
  int*   lists  = (int*)(ws + WS_LISTS);
  unsigned short* xh   = (unsigned short*)(ws + WS_XH);
  unsigned short* w1t  = (unsigned short*)(ws + WS_W1T);
  unsigned short* w2t  = (unsigned short*)(ws + WS_W2T);
  unsigned short* hbuf = (unsigned short*)(ws + WS_HBUF);

  hipMemsetAsync(ws, 0, 128, stream);                                   // counts+seg
  hipMemsetAsync(d_out, 0, (size_t)NTOK * HID * sizeof(float), stream); // atomic target

  moe_prep<<<8192 + NTOK/4, 256, 0, stream>>>(x, rw, w1, w2, xh, w1t, w2t,
                                              counts, lists, probs);
  moe_segoff<<<1, 64, 0, stream>>>(counts, seg);
  moe_gemm1<<<MAX_TILES * (FFN / BN), 256, 0, stream>>>(xh, w1t, counts, seg, lists, hbuf);
  moe_gemm2<<<MAX_TILES * (HID / BN) * 2, 256, 0, stream>>>(hbuf, w2t, counts, seg, lists, probs, out);
}